// Round 8
// baseline (586.835 us; speedup 1.0000x reference)
//
#include <hip/hip_runtime.h>
#include <hip/hip_fp16.h>

#define BATCH   65536
#define IN_DIM  784
#define KH      800      // GEMM K per half (shared-B); S2 is KH wide
#define NSTEP   25       // KH / 32
#define H_DIM   1024
#define C_DIM   10
#define BN_EPS  1e-5f
#define SLOTH   16384    // halves per LDS slot: Ahi 4096 | Alo 4096 | B 8192 (32 KB)

typedef _Float16 half8 __attribute__((ext_vector_type(8)));
typedef float    f32x4 __attribute__((ext_vector_type(4)));

#if defined(__has_builtin)
#if __has_builtin(__builtin_amdgcn_global_load_lds)
#define HAVE_ASYNC 1
#endif
#endif
#ifndef HAVE_ASYNC
#define HAVE_ASYNC 0
#endif

__device__ __forceinline__ void stage16(const _Float16* g, _Float16* ldsBase, int lane) {
#if HAVE_ASYNC
  __builtin_amdgcn_global_load_lds((const __attribute__((address_space(1))) void*)g,
                                   (__attribute__((address_space(3))) void*)ldsBase,
                                   16, 0, 0);
#else
  *(half8*)(ldsBase + lane * 8) = *(const half8*)g;
#endif
}

// ---------------------------------------------------------------------------
// K2: weight prep (unchanged from R7, known-good).
// ---------------------------------------------------------------------------
__global__ __launch_bounds__(256) void prep_w(const float* __restrict__ w1,
                                              const float* __restrict__ w2,
                                              float* __restrict__ alpha1,
                                              _Float16* __restrict__ S2,
                                              _Float16* __restrict__ S2W,
                                              float* __restrict__ A2P,
                                              float* __restrict__ colz) {
  __shared__ float red[4];
  const int tid = threadIdx.x, lane = tid & 63, wave = tid >> 6;
  const int j = blockIdx.x;
  if (j < H_DIM) {
    const float* wr = w1 + (long)j * IN_DIM;
    float s = 0.f;
    for (int k = tid; k < IN_DIM; k += 256) s += fabsf(wr[k]);
#pragma unroll
    for (int off = 32; off > 0; off >>= 1) s += __shfl_xor(s, off, 64);
    if (lane == 0) red[wave] = s;
    __syncthreads();
    if (tid == 0) alpha1[j] = (red[0] + red[1] + red[2] + red[3]) * (1.f / IN_DIM);
    _Float16* dr = S2 + (long)j * KH;
    for (int k = tid; k < KH; k += 256) {
      const float v = (k < IN_DIM) ? wr[k] : 0.f;
      dr[k] = (_Float16)((v > 0.f) ? 1.f : ((v < 0.f) ? -1.f : 0.f));
    }
  } else if (j < H_DIM + C_DIM) {
    const int c = j - H_DIM;
    const float* wr = w2 + (long)c * H_DIM;
    float s = 0.f;
    for (int k = tid; k < H_DIM; k += 256) s += fabsf(wr[k]);
#pragma unroll
    for (int off = 32; off > 0; off >>= 1) s += __shfl_xor(s, off, 64);
    if (lane == 0) red[wave] = s;
    __syncthreads();
    if (tid == 0) A2P[c] = (red[0] + red[1] + red[2] + red[3]) * (1.f / H_DIM);
    for (int k = tid; k < H_DIM; k += 256) {
      const float v = wr[k];
      S2W[(long)c * H_DIM + k] = (_Float16)((v > 0.f) ? 1.f : ((v < 0.f) ? -1.f : 0.f));
    }
  } else {
    for (int k = tid; k < 2 * H_DIM; k += 256) colz[k] = 0.f;
    for (int k = tid; k < 6 * H_DIM; k += 256) S2W[10 * H_DIM + k] = (_Float16)0.f;
    if (tid < 6) A2P[10 + tid] = 0.f;
  }
}

// ---------------------------------------------------------------------------
// K3: GEMM1  H[b][j] = alpha1[j]*(Xhi@B + Xlo@B),  M=65536, N=1024, K=800x2.
//
// R11: 128x256 tile, 8 waves (wave=64x64 out), 2-slot ring {Ahi|Alo|B} 32KB
// each = 64 KB LDS -> 2 blocks/CU (R7 diagnosis: at 1 block/CU the ~4800
// cyc/step of sync/latency stall is fully exposed; a co-resident block
// absorbs it). Simplified same-step staging:
//   per step t: [lgkmcnt(0); barrier] -> B-DMA(t+1) -> A-loads(t+1)->regs ->
//   frag reads(t) -> 32 MFMA (setprio) -> vmcnt(0) -> convert+ds_write A(t+1).
//  - vmcnt(0) before convert also guarantees B(t+1) landed (in-order) well
//    before the t+1 barrier; A-load latency hides under frag reads + MFMAs.
//  - lgkmcnt(0) before barrier publishes A-ds_writes; slot (t+1)&1's last
//    readers (step t-1) finished before the top-of-t barrier -> no race.
//  - per-acc order (hi pass then lo pass, t ascending) identical to R7 ->
//    bit-identical H.
//  - swizzles verbatim from verified family: A write chunk q^((row>>1)&3),
//    B pre-swizzled source (lane&3)^((lane>>3)&3), read chunk kc^((fr>>1)&3).
//  - XCD remap: 2048 blocks, b%8=XCD, n fastest (4 blocks sharing an x-panel
//    co-resident on one L2).
// ---------------------------------------------------------------------------
__global__ __launch_bounds__(512) void gemm1(const float* __restrict__ x,
                                             const _Float16* __restrict__ S2,
                                             const float* __restrict__ alpha1,
                                             float* __restrict__ H,
                                             float* __restrict__ colsum,
                                             float* __restrict__ colsumsq) {
  __shared__ _Float16 lds[2 * SLOTH];   // 64 KB
  const int tid  = threadIdx.x;
  const int lane = tid & 63;
  const int w    = tid >> 6;
  const int wr   = w >> 2;              // 0..1 (M dir, 64 rows each)
  const int wc   = w & 3;               // 0..3 (N dir, 64 cols each)

  const int b     = blockIdx.x;
  const int xcd   = b & 7;
  const int local = b >> 3;                       // 0..255
  const long m0   = (long)(xcd * 64 + (local >> 2)) * 128;
  const int  n0   = (local & 3) * 256;

  // A staging: row = tid>>2 (0..127), q = tid&3 (8 f32 each)
  const int rowS = tid >> 2;
  const int q    = tid & 3;
  const float* xp = x + (m0 + rowS) * (long)IN_DIM;
  const int cq = (q ^ ((rowS >> 1) & 3)) * 8;     // write-side swizzle (halves)
  const int aw = rowS * 32;

  // B staging (DMA): pre-swizzled global source chunk, linear LDS dest
  const int c8 = ((lane & 3) ^ ((lane >> 3) & 3)) * 8;
  const _Float16* bG = S2 + (long)(n0 + w * 32 + (lane >> 2)) * KH + c8;
  const int ldsW0 = (w * 32) * 32;                // within B region (8192 halves)
  const int ldsW1 = (w * 32 + 16) * 32;

  // read-side frag offsets
  const int fr = lane & 15;
  const int kc = lane >> 4;
  const int cp = (kc ^ ((fr >> 1) & 3)) * 8;
  const int aoff = (wr * 64 + fr) * 32 + cp;      // + mi*512, mi 0..3
  const int boff = (wc * 64 + fr) * 32 + cp;      // + ni*512, ni 0..3

  f32x4 acc[4][4] = {};

#define ALOAD(R0, R1, KB) do {                                               \
    if (((KB) + q * 8) <= (IN_DIM - 8)) {                                    \
      const float* src = xp + (KB) + q * 8;                                  \
      (R0) = *(const f32x4*)(src);                                           \
      (R1) = *(const f32x4*)(src + 4);                                       \
    } else { (R0) = f32x4{}; (R1) = f32x4{}; }                               \
  } while (0)

#define CONV_WRITE(R0, R1, PW, KB) do {                                      \
    half8 hh = {}, hl = {};                                                  \
    if (((KB) + q * 8) <= (IN_DIM - 8)) {                                    \
      _Pragma("unroll")                                                      \
      for (int i = 0; i < 8; ++i) {                                          \
        const float f = (i < 4) ? (R0)[i] : (R1)[i & 3];                     \
        const _Float16 h = (_Float16)f;                                      \
        hh[i] = h; hl[i] = (_Float16)(f - (float)h);                         \
      }                                                                      \
    }                                                                        \
    *(half8*)((PW) + aw + cq) = hh;                                          \
    *(half8*)((PW) + 4096 + aw + cq) = hl;                                   \
  } while (0)

  // ---- prologue: stage tile 0 into slot 0
  stage16(bG + 0,           lds + 8192 + ldsW0, lane);
  stage16(bG + 16 * KH + 0, lds + 8192 + ldsW1, lane);
  {
    f32x4 r0, r1;
    ALOAD(r0, r1, 0);
    asm volatile("s_waitcnt vmcnt(0)" ::: "memory");
    CONV_WRITE(r0, r1, (&lds[0]), 0);
  }

  for (int t = 0; t < NSTEP; ++t) {
    _Float16* Scur = &lds[(t & 1) * SLOTH];
    _Float16* Pw   = &lds[((t + 1) & 1) * SLOTH];
    const int kb = ((t + 1 < NSTEP) ? (t + 1) : (NSTEP - 1)) * 32;  // clamp: uniform

    asm volatile("s_waitcnt lgkmcnt(0)" ::: "memory");  // publish A-ds_writes
    __builtin_amdgcn_s_barrier();
    asm volatile("" ::: "memory");

    // issue next-tile staging first (B-DMA, then A-loads to regs)
    stage16(bG + kb,           Pw + 8192 + ldsW0, lane);
    stage16(bG + 16 * KH + kb, Pw + 8192 + ldsW1, lane);
    f32x4 r0, r1;
    ALOAD(r0, r1, kb);

    // frags of tile t
    half8 afh[4], afl[4], bf[4];
#pragma unroll
    for (int ni = 0; ni < 4; ++ni) bf[ni] = *(const half8*)&Scur[8192 + boff + ni * 512];
#pragma unroll
    for (int mi = 0; mi < 4; ++mi) afh[mi] = *(const half8*)&Scur[aoff + mi * 512];
#pragma unroll
    for (int mi = 0; mi < 4; ++mi) afl[mi] = *(const half8*)&Scur[4096 + aoff + mi * 512];

    __builtin_amdgcn_s_setprio(1);
#pragma unroll
    for (int mi = 0; mi < 4; ++mi)
#pragma unroll
      for (int ni = 0; ni < 4; ++ni)
        acc[mi][ni] = __builtin_amdgcn_mfma_f32_16x16x32_f16(afh[mi], bf[ni], acc[mi][ni], 0, 0, 0);
#pragma unroll
    for (int mi = 0; mi < 4; ++mi)
#pragma unroll
      for (int ni = 0; ni < 4; ++ni)
        acc[mi][ni] = __builtin_amdgcn_mfma_f32_16x16x32_f16(afl[mi], bf[ni], acc[mi][ni], 0, 0, 0);
    __builtin_amdgcn_s_setprio(0);

    // drain staging loads (covers B-DMA too, in-order), then convert+write
    asm volatile("s_waitcnt vmcnt(0)" ::: "memory");
    CONV_WRITE(r0, r1, Pw, kb);
  }

  asm volatile("s_waitcnt vmcnt(0)" ::: "memory");   // safety drain

  // epilogue: D layout col=lane&15, row=(lane>>4)*4+r + fused col sum/sumsq
  const int rq = (lane >> 4) * 4;
#pragma unroll
  for (int ni = 0; ni < 4; ++ni) {
    const int col = n0 + wc * 64 + ni * 16 + fr;
    const float a1 = alpha1[col];
    float s = 0.f, qq = 0.f;
#pragma unroll
    for (int mi = 0; mi < 4; ++mi) {
#pragma unroll
      for (int r = 0; r < 4; ++r) {
        const long row = m0 + wr * 64 + mi * 16 + rq + r;
        const float v = acc[mi][ni][r] * a1;
        H[row * H_DIM + col] = v;
        s += v;
        qq += v * v;
      }
    }
    s += __shfl_xor(s, 16, 64);
    s += __shfl_xor(s, 32, 64);
    qq += __shfl_xor(qq, 16, 64);
    qq += __shfl_xor(qq, 32, 64);
    if ((lane >> 4) == 0) {
      atomicAdd(&colsum[col], s);
      atomicAdd(&colsumsq[col], qq);
    }
  }
#undef ALOAD
#undef CONV_WRITE
}

// ---------------------------------------------------------------------------
// K5 (unchanged from R7, known-good): normalize -> sign -> GEMM2 via MFMA,
// out via LDS bounce + one coalesced 2560-B block write.
// ---------------------------------------------------------------------------
__global__ __launch_bounds__(256) void final_k(const float* __restrict__ H,
                                               const float* __restrict__ colsum,
                                               const float* __restrict__ colsumsq,
                                               const float* __restrict__ gamma,
                                               const float* __restrict__ beta,
                                               const _Float16* __restrict__ S2W,
                                               const float* __restrict__ A2P,
                                               float* __restrict__ out) {
  __shared__ _Float16 bs[16 * H_DIM];   // 32 KB, swizzled; tail reused for out staging
  __shared__ float cs[H_DIM], ts[H_DIM];
  const int tid = threadIdx.x, lane = tid & 63, wave = tid >> 6;

  {  // cs/ts: one f32x4 per thread covers all 1024 cols
    const int j = tid * 4;
    const f32x4 s  = *(const f32x4*)&colsum[j];
    const f32x4 q  = *(const f32x4*)&colsumsq[j];
    const f32x4 g  = *(const f32x4*)&gamma[j];
    const f32x4 bt = *(const f32x4*)&beta[j];
    f32x4 c, t;
#pragma unroll
    for (int i = 0; i < 4; ++i) {
      const float mu  = s[i] * (1.f / BATCH);
      const float var = q[i] * (1.f / BATCH) - mu * mu;
      c[i] = g[i] * rsqrtf(var + BN_EPS);
      t[i] = bt[i] - c[i] * mu;
    }
    *(f32x4*)&cs[j] = c;
    *(f32x4*)&ts[j] = t;
  }
  for (int i = tid; i < 2048; i += 256) {       // 16 rows x 128 chunks of 8 halves
    const int oc = i >> 7, cc = i & 127;
    *(half8*)&bs[oc * H_DIM + ((cc ^ (oc & 7)) << 3)] = *(const half8*)&S2W[oc * H_DIM + (cc << 3)];
  }
  __syncthreads();

  const int lr = lane & 15, lg = lane >> 4;
  const float alf = A2P[lr];
  const long r0 = ((long)blockIdx.x * 4 + wave) * 16;   // grid = BATCH/64
  const float* hp = H + (r0 + lr) * H_DIM + lg * 8;

  f32x4 acc = {};
#pragma unroll 4
  for (int ks = 0; ks < 32; ++ks) {
    const f32x4 h0 = *(const f32x4*)(hp + ks * 32);
    const f32x4 h1 = *(const f32x4*)(hp + ks * 32 + 4);
    const int jb = ks * 32 + lg * 8;
    const f32x4 c0v = *(const f32x4*)&cs[jb];
    const f32x4 c1v = *(const f32x4*)&cs[jb + 4];
    const f32x4 t0v = *(const f32x4*)&ts[jb];
    const f32x4 t1v = *(const f32x4*)&ts[jb + 4];
    half8 afr;
#pragma unroll
    for (int i = 0; i < 4; ++i) {
      const float hv = h0[i] * c0v[i] + t0v[i];
      afr[i] = (_Float16)((hv > 0.f) ? 1.f : ((hv < 0.f) ? -1.f : 0.f));
    }
#pragma unroll
    for (int i = 0; i < 4; ++i) {
      const float hv = h1[i] * c1v[i] + t1v[i];
      afr[4 + i] = (_Float16)((hv > 0.f) ? 1.f : ((hv < 0.f) ? -1.f : 0.f));
    }
    const int cc = (ks * 4 + lg) ^ (lr & 7);
    const half8 bfr = *(const half8*)&bs[lr * H_DIM + cc * 8];
    acc = __builtin_amdgcn_mfma_f32_16x16x32_f16(afr, bfr, acc, 0, 0, 0);
  }

  __syncthreads();
  float* outs = (float*)bs;            // 640 floats = [64 rows][10 cols]
  if (lr < C_DIM) {
#pragma unroll
    for (int r = 0; r < 4; ++r)
      outs[(wave * 16 + lg * 4 + r) * C_DIM + lr] = acc[r] * alf;
  }
  __syncthreads();
  if (tid < 160)
    *(f32x4*)&out[(long)blockIdx.x * 640 + tid * 4] = *(const f32x4*)&outs[tid * 4];
}

// ---------------------------------------------------------------------------
extern "C" void kernel_launch(void* const* d_in, const int* in_sizes, int n_in,
                              void* d_out, int out_size, void* d_ws, size_t ws_size,
                              hipStream_t stream) {
  const float* x     = (const float*)d_in[0];
  const float* w1    = (const float*)d_in[1];
  const float* w2    = (const float*)d_in[2];
  const float* gamma = (const float*)d_in[3];
  const float* beta  = (const float*)d_in[4];
  float* out = (float*)d_out;

  // workspace layout (bytes), 256B-aligned; total ~270.1 MB
  char* ws = (char*)d_ws;
  float*    H      = (float*)   (ws + 0);             // 268,435,456
  _Float16* S2     = (_Float16*)(ws + 268435456LL);   // 1024*800*2 = 1,638,400
  _Float16* S2W    = (_Float16*)(ws + 270073856LL);   // 16*1024*2  =    32,768
  float*    ALPHA1 = (float*)   (ws + 270106624LL);   // 1024*4
  float*    A2P    = (float*)   (ws + 270110720LL);   // 16*4 (pad to 256)
  float*    COLS   = (float*)   (ws + 270110976LL);   // 1024*4
  float*    COLQ   = (float*)   (ws + 270115072LL);   // 1024*4

  prep_w<<<H_DIM + C_DIM + 1, 256, 0, stream>>>(w1, w2, ALPHA1, S2, S2W, A2P, COLS);
  gemm1<<<2048, 512, 0, stream>>>(x, S2, ALPHA1, H, COLS, COLQ);
  final_k<<<BATCH / 64, 256, 0, stream>>>(H, COLS, COLQ, gamma, beta, S2W, A2P, out);
}

// Round 9
// 534.283 us; speedup vs baseline: 1.0984x; 1.0984x over previous
//
#include <hip/hip_runtime.h>
#include <hip/hip_fp16.h>

#define BATCH   65536
#define IN_DIM  784
#define KH      800      // GEMM K per half (shared-B); S2 is KH wide
#define NSTEP   25       // KH / 32
#define H_DIM   1024
#define C_DIM   10
#define BN_EPS  1e-5f
#define SLOTH   16384    // halves per LDS slot: Ahi 4096 | Alo 4096 | B 8192 (32 KB)

typedef _Float16 half8 __attribute__((ext_vector_type(8)));
typedef float    f32x4 __attribute__((ext_vector_type(4)));

#if defined(__has_builtin)
#if __has_builtin(__builtin_amdgcn_global_load_lds)
#define HAVE_ASYNC 1
#endif
#endif
#ifndef HAVE_ASYNC
#define HAVE_ASYNC 0
#endif

__device__ __forceinline__ void stage16(const _Float16* g, _Float16* ldsBase, int lane) {
#if HAVE_ASYNC
  __builtin_amdgcn_global_load_lds((const __attribute__((address_space(1))) void*)g,
                                   (__attribute__((address_space(3))) void*)ldsBase,
                                   16, 0, 0);
#else
  *(half8*)(ldsBase + lane * 8) = *(const half8*)g;
#endif
}

// ---------------------------------------------------------------------------
// K2: weight prep (unchanged, known-good).
// ---------------------------------------------------------------------------
__global__ __launch_bounds__(256) void prep_w(const float* __restrict__ w1,
                                              const float* __restrict__ w2,
                                              float* __restrict__ alpha1,
                                              _Float16* __restrict__ S2,
                                              _Float16* __restrict__ S2W,
                                              float* __restrict__ A2P,
                                              float* __restrict__ colz) {
  __shared__ float red[4];
  const int tid = threadIdx.x, lane = tid & 63, wave = tid >> 6;
  const int j = blockIdx.x;
  if (j < H_DIM) {
    const float* wr = w1 + (long)j * IN_DIM;
    float s = 0.f;
    for (int k = tid; k < IN_DIM; k += 256) s += fabsf(wr[k]);
#pragma unroll
    for (int off = 32; off > 0; off >>= 1) s += __shfl_xor(s, off, 64);
    if (lane == 0) red[wave] = s;
    __syncthreads();
    if (tid == 0) alpha1[j] = (red[0] + red[1] + red[2] + red[3]) * (1.f / IN_DIM);
    _Float16* dr = S2 + (long)j * KH;
    for (int k = tid; k < KH; k += 256) {
      const float v = (k < IN_DIM) ? wr[k] : 0.f;
      dr[k] = (_Float16)((v > 0.f) ? 1.f : ((v < 0.f) ? -1.f : 0.f));
    }
  } else if (j < H_DIM + C_DIM) {
    const int c = j - H_DIM;
    const float* wr = w2 + (long)c * H_DIM;
    float s = 0.f;
    for (int k = tid; k < H_DIM; k += 256) s += fabsf(wr[k]);
#pragma unroll
    for (int off = 32; off > 0; off >>= 1) s += __shfl_xor(s, off, 64);
    if (lane == 0) red[wave] = s;
    __syncthreads();
    if (tid == 0) A2P[c] = (red[0] + red[1] + red[2] + red[3]) * (1.f / H_DIM);
    for (int k = tid; k < H_DIM; k += 256) {
      const float v = wr[k];
      S2W[(long)c * H_DIM + k] = (_Float16)((v > 0.f) ? 1.f : ((v < 0.f) ? -1.f : 0.f));
    }
  } else {
    for (int k = tid; k < 2 * H_DIM; k += 256) colz[k] = 0.f;
    for (int k = tid; k < 6 * H_DIM; k += 256) S2W[10 * H_DIM + k] = (_Float16)0.f;
    if (tid < 6) A2P[10 + tid] = 0.f;
  }
}

// ---------------------------------------------------------------------------
// K3: GEMM1  H[b][j] = alpha1[j]*(Xhi@B + Xlo@B),  M=65536, N=1024, K=800x2.
//
// R12 = R8 + __launch_bounds__(512, 4). R8 post-mortem: trace VGPR=72 EXCLUDES
// the 64 acc AGPRs; true 136 regs/wave -> 3 waves/SIMD -> a second 8-wave
// block (needs 4/SIMD) never fit. Every round so far ran 1 block/CU; all
// occupancy/pipeline nulls follow. The (512,4) bound caps regs at 128/wave,
// admitting 2 blocks/CU (128KB LDS <= 160KB), so the ~4.8k cyc/step of
// latency/sync stall overlaps with the co-resident block.
// Frag reads reordered (bf+afh -> hi MFMA -> afl -> lo MFMA) to cut peak
// live regs (~96 + staging/addr); per-acc accumulation order unchanged ->
// bit-identical H.
// ---------------------------------------------------------------------------
__global__ __launch_bounds__(512, 4) void gemm1(const float* __restrict__ x,
                                                const _Float16* __restrict__ S2,
                                                const float* __restrict__ alpha1,
                                                float* __restrict__ H,
                                                float* __restrict__ colsum,
                                                float* __restrict__ colsumsq) {
  __shared__ _Float16 lds[2 * SLOTH];   // 64 KB
  const int tid  = threadIdx.x;
  const int lane = tid & 63;
  const int w    = tid >> 6;
  const int wr   = w >> 2;              // 0..1 (M dir, 64 rows each)
  const int wc   = w & 3;               // 0..3 (N dir, 64 cols each)

  const int b     = blockIdx.x;
  const int xcd   = b & 7;
  const int local = b >> 3;                       // 0..255
  const long m0   = (long)(xcd * 64 + (local >> 2)) * 128;
  const int  n0   = (local & 3) * 256;

  // A staging: row = tid>>2 (0..127), q = tid&3 (8 f32 each)
  const int rowS = tid >> 2;
  const int q    = tid & 3;
  const float* xp = x + (m0 + rowS) * (long)IN_DIM;
  const int cq = (q ^ ((rowS >> 1) & 3)) * 8;     // write-side swizzle (halves)
  const int aw = rowS * 32;

  // B staging (DMA): pre-swizzled global source chunk, linear LDS dest
  const int c8 = ((lane & 3) ^ ((lane >> 3) & 3)) * 8;
  const _Float16* bG = S2 + (long)(n0 + w * 32 + (lane >> 2)) * KH + c8;
  const int ldsW0 = (w * 32) * 32;                // within B region (8192 halves)
  const int ldsW1 = (w * 32 + 16) * 32;

  // read-side frag offsets
  const int fr = lane & 15;
  const int kc = lane >> 4;
  const int cp = (kc ^ ((fr >> 1) & 3)) * 8;
  const int aoff = (wr * 64 + fr) * 32 + cp;      // + mi*512, mi 0..3
  const int boff = (wc * 64 + fr) * 32 + cp;      // + ni*512, ni 0..3

  f32x4 acc[4][4] = {};

#define ALOAD(R0, R1, KB) do {                                               \
    if (((KB) + q * 8) <= (IN_DIM - 8)) {                                    \
      const float* src = xp + (KB) + q * 8;                                  \
      (R0) = *(const f32x4*)(src);                                           \
      (R1) = *(const f32x4*)(src + 4);                                       \
    } else { (R0) = f32x4{}; (R1) = f32x4{}; }                               \
  } while (0)

#define CONV_WRITE(R0, R1, PW, KB) do {                                      \
    half8 hh = {}, hl = {};                                                  \
    if (((KB) + q * 8) <= (IN_DIM - 8)) {                                    \
      _Pragma("unroll")                                                      \
      for (int i = 0; i < 8; ++i) {                                          \
        const float f = (i < 4) ? (R0)[i] : (R1)[i & 3];                     \
        const _Float16 h = (_Float16)f;                                      \
        hh[i] = h; hl[i] = (_Float16)(f - (float)h);                         \
      }                                                                      \
    }                                                                        \
    *(half8*)((PW) + aw + cq) = hh;                                          \
    *(half8*)((PW) + 4096 + aw + cq) = hl;                                   \
  } while (0)

  // ---- prologue: stage tile 0 into slot 0
  stage16(bG + 0,           lds + 8192 + ldsW0, lane);
  stage16(bG + 16 * KH + 0, lds + 8192 + ldsW1, lane);
  {
    f32x4 r0, r1;
    ALOAD(r0, r1, 0);
    asm volatile("s_waitcnt vmcnt(0)" ::: "memory");
    CONV_WRITE(r0, r1, (&lds[0]), 0);
  }

  for (int t = 0; t < NSTEP; ++t) {
    _Float16* Scur = &lds[(t & 1) * SLOTH];
    _Float16* Pw   = &lds[((t + 1) & 1) * SLOTH];
    const int kb = ((t + 1 < NSTEP) ? (t + 1) : (NSTEP - 1)) * 32;  // clamp: uniform

    asm volatile("s_waitcnt lgkmcnt(0)" ::: "memory");  // publish A-ds_writes
    __builtin_amdgcn_s_barrier();
    asm volatile("" ::: "memory");

    // issue next-tile staging first (B-DMA, then A-loads to regs)
    stage16(bG + kb,           Pw + 8192 + ldsW0, lane);
    stage16(bG + 16 * KH + kb, Pw + 8192 + ldsW1, lane);
    f32x4 r0, r1;
    ALOAD(r0, r1, kb);

    // frags of tile t: bf + A-hi, hi-MFMAs; then A-lo reuses the window
    half8 af[4], bf[4];
#pragma unroll
    for (int ni = 0; ni < 4; ++ni) bf[ni] = *(const half8*)&Scur[8192 + boff + ni * 512];
#pragma unroll
    for (int mi = 0; mi < 4; ++mi) af[mi] = *(const half8*)&Scur[aoff + mi * 512];
    __builtin_amdgcn_s_setprio(1);
#pragma unroll
    for (int mi = 0; mi < 4; ++mi)
#pragma unroll
      for (int ni = 0; ni < 4; ++ni)
        acc[mi][ni] = __builtin_amdgcn_mfma_f32_16x16x32_f16(af[mi], bf[ni], acc[mi][ni], 0, 0, 0);
    __builtin_amdgcn_s_setprio(0);
#pragma unroll
    for (int mi = 0; mi < 4; ++mi) af[mi] = *(const half8*)&Scur[4096 + aoff + mi * 512];
    __builtin_amdgcn_s_setprio(1);
#pragma unroll
    for (int mi = 0; mi < 4; ++mi)
#pragma unroll
      for (int ni = 0; ni < 4; ++ni)
        acc[mi][ni] = __builtin_amdgcn_mfma_f32_16x16x32_f16(af[mi], bf[ni], acc[mi][ni], 0, 0, 0);
    __builtin_amdgcn_s_setprio(0);

    // drain staging loads (covers B-DMA too, in-order), then convert+write
    asm volatile("s_waitcnt vmcnt(0)" ::: "memory");
    CONV_WRITE(r0, r1, Pw, kb);
  }

  asm volatile("s_waitcnt vmcnt(0)" ::: "memory");   // safety drain

  // epilogue: D layout col=lane&15, row=(lane>>4)*4+r + fused col sum/sumsq
  const int rq = (lane >> 4) * 4;
#pragma unroll
  for (int ni = 0; ni < 4; ++ni) {
    const int col = n0 + wc * 64 + ni * 16 + fr;
    const float a1 = alpha1[col];
    float s = 0.f, qq = 0.f;
#pragma unroll
    for (int mi = 0; mi < 4; ++mi) {
#pragma unroll
      for (int r = 0; r < 4; ++r) {
        const long row = m0 + wr * 64 + mi * 16 + rq + r;
        const float v = acc[mi][ni][r] * a1;
        H[row * H_DIM + col] = v;
        s += v;
        qq += v * v;
      }
    }
    s += __shfl_xor(s, 16, 64);
    s += __shfl_xor(s, 32, 64);
    qq += __shfl_xor(qq, 16, 64);
    qq += __shfl_xor(qq, 32, 64);
    if ((lane >> 4) == 0) {
      atomicAdd(&colsum[col], s);
      atomicAdd(&colsumsq[col], qq);
    }
  }
#undef ALOAD
#undef CONV_WRITE
}

// ---------------------------------------------------------------------------
// K5 (unchanged, known-good): normalize -> sign -> GEMM2 via MFMA,
// out via LDS bounce + one coalesced 2560-B block write.
// ---------------------------------------------------------------------------
__global__ __launch_bounds__(256) void final_k(const float* __restrict__ H,
                                               const float* __restrict__ colsum,
                                               const float* __restrict__ colsumsq,
                                               const float* __restrict__ gamma,
                                               const float* __restrict__ beta,
                                               const _Float16* __restrict__ S2W,
                                               const float* __restrict__ A2P,
                                               float* __restrict__ out) {
  __shared__ _Float16 bs[16 * H_DIM];   // 32 KB, swizzled; tail reused for out staging
  __shared__ float cs[H_DIM], ts[H_DIM];
  const int tid = threadIdx.x, lane = tid & 63, wave = tid >> 6;

  {  // cs/ts: one f32x4 per thread covers all 1024 cols
    const int j = tid * 4;
    const f32x4 s  = *(const f32x4*)&colsum[j];
    const f32x4 q  = *(const f32x4*)&colsumsq[j];
    const f32x4 g  = *(const f32x4*)&gamma[j];
    const f32x4 bt = *(const f32x4*)&beta[j];
    f32x4 c, t;
#pragma unroll
    for (int i = 0; i < 4; ++i) {
      const float mu  = s[i] * (1.f / BATCH);
      const float var = q[i] * (1.f / BATCH) - mu * mu;
      c[i] = g[i] * rsqrtf(var + BN_EPS);
      t[i] = bt[i] - c[i] * mu;
    }
    *(f32x4*)&cs[j] = c;
    *(f32x4*)&ts[j] = t;
  }
  for (int i = tid; i < 2048; i += 256) {       // 16 rows x 128 chunks of 8 halves
    const int oc = i >> 7, cc = i & 127;
    *(half8*)&bs[oc * H_DIM + ((cc ^ (oc & 7)) << 3)] = *(const half8*)&S2W[oc * H_DIM + (cc << 3)];
  }
  __syncthreads();

  const int lr = lane & 15, lg = lane >> 4;
  const float alf = A2P[lr];
  const long r0 = ((long)blockIdx.x * 4 + wave) * 16;   // grid = BATCH/64
  const float* hp = H + (r0 + lr) * H_DIM + lg * 8;

  f32x4 acc = {};
#pragma unroll 4
  for (int ks = 0; ks < 32; ++ks) {
    const f32x4 h0 = *(const f32x4*)(hp + ks * 32);
    const f32x4 h1 = *(const f32x4*)(hp + ks * 32 + 4);
    const int jb = ks * 32 + lg * 8;
    const f32x4 c0v = *(const f32x4*)&cs[jb];
    const f32x4 c1v = *(const f32x4*)&cs[jb + 4];
    const f32x4 t0v = *(const f32x4*)&ts[jb];
    const f32x4 t1v = *(const f32x4*)&ts[jb + 4];
    half8 afr;
#pragma unroll
    for (int i = 0; i < 4; ++i) {
      const float hv = h0[i] * c0v[i] + t0v[i];
      afr[i] = (_Float16)((hv > 0.f) ? 1.f : ((hv < 0.f) ? -1.f : 0.f));
    }
#pragma unroll
    for (int i = 0; i < 4; ++i) {
      const float hv = h1[i] * c1v[i] + t1v[i];
      afr[4 + i] = (_Float16)((hv > 0.f) ? 1.f : ((hv < 0.f) ? -1.f : 0.f));
    }
    const int cc = (ks * 4 + lg) ^ (lr & 7);
    const half8 bfr = *(const half8*)&bs[lr * H_DIM + cc * 8];
    acc = __builtin_amdgcn_mfma_f32_16x16x32_f16(afr, bfr, acc, 0, 0, 0);
  }

  __syncthreads();
  float* outs = (float*)bs;            // 640 floats = [64 rows][10 cols]
  if (lr < C_DIM) {
#pragma unroll
    for (int r = 0; r < 4; ++r)
      outs[(wave * 16 + lg * 4 + r) * C_DIM + lr] = acc[r] * alf;
  }
  __syncthreads();
  if (tid < 160)
    *(f32x4*)&out[(long)blockIdx.x * 640 + tid * 4] = *(const f32x4*)&outs[tid * 4];
}

// ---------------------------------------------------------------------------
extern "C" void kernel_launch(void* const* d_in, const int* in_sizes, int n_in,
                              void* d_out, int out_size, void* d_ws, size_t ws_size,
                              hipStream_t stream) {
  const float* x     = (const float*)d_in[0];
  const float* w1    = (const float*)d_in[1];
  const float* w2    = (const float*)d_in[2];
  const float* gamma = (const float*)d_in[3];
  const float* beta  = (const float*)d_in[4];
  float* out = (float*)d_out;

  // workspace layout (bytes), 256B-aligned; total ~270.1 MB
  char* ws = (char*)d_ws;
  float*    H      = (float*)   (ws + 0);             // 268,435,456
  _Float16* S2     = (_Float16*)(ws + 268435456LL);   // 1024*800*2 = 1,638,400
  _Float16* S2W    = (_Float16*)(ws + 270073856LL);   // 16*1024*2  =    32,768
  float*    ALPHA1 = (float*)   (ws + 270106624LL);   // 1024*4
  float*    A2P    = (float*)   (ws + 270110720LL);   // 16*4 (pad to 256)
  float*    COLS   = (float*)   (ws + 270110976LL);   // 1024*4
  float*    COLQ   = (float*)   (ws + 270115072LL);   // 1024*4

  prep_w<<<H_DIM + C_DIM + 1, 256, 0, stream>>>(w1, w2, ALPHA1, S2, S2W, A2P, COLS);
  gemm1<<<2048, 512, 0, stream>>>(x, S2, ALPHA1, H, COLS, COLQ);
  final_k<<<BATCH / 64, 256, 0, stream>>>(H, COLS, COLQ, gamma, beta, S2W, A2P, out);
}